// Round 8
// baseline (913.263 us; speedup 1.0000x reference)
//
#include <hip/hip_runtime.h>
#include <hip/hip_bf16.h>
#include <cstdint>
#include <cstddef>

#define B_    8
#define L_    256
#define DM_   1024
#define DI_   2048
#define N_    16
#define K_    4
#define NL_   4
#define DTR_  128
#define P_    97
#define XPD_  160   // DTR + 2N
#define CHUNK_ 32
#define NC_   8     // L / CHUNK

typedef __attribute__((ext_vector_type(8))) short short8;
typedef __attribute__((ext_vector_type(4))) float floatx4;

__device__ __forceinline__ void async16(const void* g, void* l)
{
    __builtin_amdgcn_global_load_lds(
        (const __attribute__((address_space(1))) void*)g,
        (__attribute__((address_space(3))) void*)l,
        16, 0, 0);
}

__device__ __forceinline__ float bf2f(__hip_bfloat16 h) { return __bfloat162float(h); }

// ---------------------------------------------------------------------------
// Embedding + layer-0 LayerNorm. One block per (b,l) row.
// ---------------------------------------------------------------------------
__global__ __launch_bounds__(256)
void embed_ln_k(const int* __restrict__ tokens, const float* __restrict__ te,
                const float* __restrict__ pe, const float* __restrict__ lw,
                const float* __restrict__ lb, float* __restrict__ h,
                __hip_bfloat16* __restrict__ xout)
{
    __shared__ float red[8];
    int bl = blockIdx.x;
    int l  = bl & (L_ - 1);
    int tok = tokens[bl];
    int tid = threadIdx.x;
    float4 a = *(const float4*)(te + (size_t)tok * DM_ + tid * 4);
    float4 p = *(const float4*)(pe + (size_t)l * DM_ + tid * 4);
    float4 x = make_float4(a.x + p.x, a.y + p.y, a.z + p.z, a.w + p.w);
    size_t base = (size_t)bl * DM_ + tid * 4;
    *(float4*)(h + base) = x;

    float s  = x.x + x.y + x.z + x.w;
    float s2 = x.x * x.x + x.y * x.y + x.z * x.z + x.w * x.w;
    #pragma unroll
    for (int o = 32; o > 0; o >>= 1) {
        s  += __shfl_down(s, o);
        s2 += __shfl_down(s2, o);
    }
    if ((tid & 63) == 0) { red[tid >> 6] = s; red[4 + (tid >> 6)] = s2; }
    __syncthreads();
    float st  = red[0] + red[1] + red[2] + red[3];
    float s2t = red[4] + red[5] + red[6] + red[7];
    float m   = st * (1.f / DM_);
    float var = s2t * (1.f / DM_) - m * m;
    float rs  = rsqrtf(var + 1e-5f);
    float4 wv = *(const float4*)(lw + tid * 4);
    float4 bv = *(const float4*)(lb + tid * 4);
    union { __hip_bfloat16 h[4]; ushort4 u; } t;
    t.h[0] = __float2bfloat16((x.x - m) * rs * wv.x + bv.x);
    t.h[1] = __float2bfloat16((x.y - m) * rs * wv.y + bv.y);
    t.h[2] = __float2bfloat16((x.z - m) * rs * wv.z + bv.z);
    t.h[3] = __float2bfloat16((x.w - m) * rs * wv.w + bv.w);
    *(ushort4*)(xout + base) = t.u;
}

// ---------------------------------------------------------------------------
// MFMA GEMM: A bf16 (async->LDS), B **fp32** (VGPR staging + cvt -> LDS).
// 128xTN tile (TN = 128 or 64), BK=32.
// MODE 0: full-K -> bf16 C
// MODE 2: split-K partial -> fp32 Cp[z][M][ldc]
// MODE 3: split-K partial fp32, B-row guard (rows >= NbRows -> 0) and
//         epilogue col < NbRows guard (xproj, raw 160-row weights)
// MODE 5: full-K, bias+softplus -> bf16 C (dt matmul)
// ---------------------------------------------------------------------------
template<int MODE, int TN>
__global__ __launch_bounds__(256)
void gemm_wf32(const __hip_bfloat16* __restrict__ A, int lda,
               const float* __restrict__ Bw, int ldb,
               void* __restrict__ Cv, int ldc, int Kp, int NbRows,
               const float* __restrict__ bias)
{
    constexpr int JW  = (TN == 128) ? 4 : 2;
    constexpr int EPT = (TN * 32) / 256;     // B elems per thread: 16 or 8
    __shared__ __hip_bfloat16 As[128 * 32];
    __shared__ __hip_bfloat16 Bs[TN * 32];
    const int tid  = threadIdx.x;
    const int lane = tid & 63;
    const int wid  = tid >> 6;
    const int wm   = wid >> 1, wn = wid & 1;
    const int mbase = blockIdx.y * 128;
    const int nbase = blockIdx.x * TN;
    const int koff  = (MODE == 2 || MODE == 3) ? blockIdx.z * Kp : 0;

    floatx4 acc[4][JW] = {};

    // A staging map (bytes): 128 rows x 64 B
    const int f0 = tid * 16;
    const int r0 = f0 >> 6, c0 = f0 & 63;
    const int f1 = f0 + 4096;
    const int r1 = f1 >> 6, c1 = f1 & 63;

    // B staging map (elems): TN rows x 32 k
    const int bf   = tid * EPT;
    const int brow = bf >> 5;
    const int bcol = bf & 31;
    const bool bok = (MODE != 3) || (nbase + brow) < NbRows;
    const float* Bbase = Bw + (size_t)(nbase + brow) * ldb + bcol;

    const int fr = lane & 15;
    const int kq = (lane >> 4) * 8;

    for (int k0 = koff; k0 < koff + Kp; k0 += 32) {
        const char* Ag = (const char*)(A + (size_t)mbase * lda + k0);
        async16(Ag + (size_t)r0 * lda * 2 + c0, (char*)As + f0);
        async16(Ag + (size_t)r1 * lda * 2 + c1, (char*)As + f1);
        {
            float4 v0 = make_float4(0.f, 0.f, 0.f, 0.f), v1 = v0;
            if (bok) {
                v0 = *(const float4*)(Bbase + k0);
                v1 = *(const float4*)(Bbase + k0 + 4);
            }
            union { __hip_bfloat16 h[8]; short8 u; } tb;
            tb.h[0] = __float2bfloat16(v0.x); tb.h[1] = __float2bfloat16(v0.y);
            tb.h[2] = __float2bfloat16(v0.z); tb.h[3] = __float2bfloat16(v0.w);
            tb.h[4] = __float2bfloat16(v1.x); tb.h[5] = __float2bfloat16(v1.y);
            tb.h[6] = __float2bfloat16(v1.z); tb.h[7] = __float2bfloat16(v1.w);
            *(short8*)(Bs + bf) = tb.u;
            if constexpr (EPT == 16) {
                float4 v2 = make_float4(0.f, 0.f, 0.f, 0.f), v3 = v2;
                if (bok) {
                    v2 = *(const float4*)(Bbase + k0 + 8);
                    v3 = *(const float4*)(Bbase + k0 + 12);
                }
                union { __hip_bfloat16 h[8]; short8 u; } tc;
                tc.h[0] = __float2bfloat16(v2.x); tc.h[1] = __float2bfloat16(v2.y);
                tc.h[2] = __float2bfloat16(v2.z); tc.h[3] = __float2bfloat16(v2.w);
                tc.h[4] = __float2bfloat16(v3.x); tc.h[5] = __float2bfloat16(v3.y);
                tc.h[6] = __float2bfloat16(v3.z); tc.h[7] = __float2bfloat16(v3.w);
                *(short8*)(Bs + bf + 8) = tc.u;
            }
        }
        __syncthreads();

        short8 af[4], bfr[JW];
        #pragma unroll
        for (int i = 0; i < 4; ++i) {
            int m = wm * 64 + i * 16 + fr;
            af[i] = *(const short8*)(As + m * 32 + kq);
        }
        #pragma unroll
        for (int j = 0; j < JW; ++j) {
            int n = wn * (TN / 2) + j * 16 + fr;
            bfr[j] = *(const short8*)(Bs + n * 32 + kq);
        }
        #pragma unroll
        for (int i = 0; i < 4; ++i)
            #pragma unroll
            for (int j = 0; j < JW; ++j)
                acc[i][j] = __builtin_amdgcn_mfma_f32_16x16x32_bf16(
                    af[i], bfr[j], acc[i][j], 0, 0, 0);
        __syncthreads();
    }

    const int cq = lane >> 4;
    float* Cf = (float*)Cv;
    __hip_bfloat16* Ch = (__hip_bfloat16*)Cv;
    size_t zoff = (MODE == 2 || MODE == 3)
                ? (size_t)blockIdx.z * (gridDim.y * 128) * ldc : 0;
    #pragma unroll
    for (int i = 0; i < 4; ++i) {
        #pragma unroll
        for (int j = 0; j < JW; ++j) {
            int col = nbase + wn * (TN / 2) + j * 16 + fr;
            if (MODE == 3 && col >= NbRows) continue;
            float bv = (MODE == 5) ? bias[col] : 0.f;
            #pragma unroll
            for (int r = 0; r < 4; ++r) {
                int row = mbase + wm * 64 + i * 16 + cq * 4 + r;
                float v = acc[i][j][r];
                size_t off = zoff + (size_t)row * ldc + col;
                if (MODE == 2 || MODE == 3) {
                    Cf[off] = v;
                } else if (MODE == 5) {
                    v += bv;
                    v = (v > 20.f) ? v : log1pf(__expf(v));
                    Ch[off] = __float2bfloat16(v);
                } else {
                    Ch[off] = __float2bfloat16(v);
                }
            }
        }
    }
}

// ---------------------------------------------------------------------------
// Split-K reduce for xp: emit fp32 xp AND bf16 xp_b
// ---------------------------------------------------------------------------
template<int PARTS>
__global__ __launch_bounds__(256)
void reduce_xp_k(const float* __restrict__ p, float* __restrict__ dst,
                 __hip_bfloat16* __restrict__ dst_b, size_t stride)
{
    size_t i = ((size_t)blockIdx.x * 256 + threadIdx.x) * 4;
    float4 s = *(const float4*)(p + i);
    #pragma unroll
    for (int z = 1; z < PARTS; ++z) {
        float4 v = *(const float4*)(p + z * stride + i);
        s.x += v.x; s.y += v.y; s.z += v.z; s.w += v.w;
    }
    *(float4*)(dst + i) = s;
    union { __hip_bfloat16 h[4]; ushort4 u; } t;
    t.h[0] = __float2bfloat16(s.x);
    t.h[1] = __float2bfloat16(s.y);
    t.h[2] = __float2bfloat16(s.z);
    t.h[3] = __float2bfloat16(s.w);
    *(ushort4*)(dst_b + i) = t.u;
}

// ---------------------------------------------------------------------------
// Fused: h[row] += sum_z part[z][row]; then LayerNorm(h[row]) -> bf16 out.
// ---------------------------------------------------------------------------
template<int PARTS>
__global__ __launch_bounds__(256)
void reduce_ln_k(const float* __restrict__ p, float* __restrict__ h,
                 const float* __restrict__ w, const float* __restrict__ b,
                 __hip_bfloat16* __restrict__ out, size_t stride)
{
    __shared__ float red[8];
    int tid = threadIdx.x;
    size_t base = (size_t)blockIdx.x * DM_ + tid * 4;
    float4 x = *(const float4*)(h + base);
    #pragma unroll
    for (int z = 0; z < PARTS; ++z) {
        float4 v = *(const float4*)(p + z * stride + base);
        x.x += v.x; x.y += v.y; x.z += v.z; x.w += v.w;
    }
    *(float4*)(h + base) = x;

    float s  = x.x + x.y + x.z + x.w;
    float s2 = x.x * x.x + x.y * x.y + x.z * x.z + x.w * x.w;
    #pragma unroll
    for (int o = 32; o > 0; o >>= 1) {
        s  += __shfl_down(s, o);
        s2 += __shfl_down(s2, o);
    }
    if ((tid & 63) == 0) { red[tid >> 6] = s; red[4 + (tid >> 6)] = s2; }
    __syncthreads();
    float st  = red[0] + red[1] + red[2] + red[3];
    float s2t = red[4] + red[5] + red[6] + red[7];
    float m   = st * (1.f / DM_);
    float var = s2t * (1.f / DM_) - m * m;
    float rs  = rsqrtf(var + 1e-5f);
    float4 wv = *(const float4*)(w + tid * 4);
    float4 bv = *(const float4*)(b + tid * 4);
    union { __hip_bfloat16 h[4]; ushort4 u; } t;
    t.h[0] = __float2bfloat16((x.x - m) * rs * wv.x + bv.x);
    t.h[1] = __float2bfloat16((x.y - m) * rs * wv.y + bv.y);
    t.h[2] = __float2bfloat16((x.z - m) * rs * wv.z + bv.z);
    t.h[3] = __float2bfloat16((x.w - m) * rs * wv.w + bv.w);
    *(ushort4*)(out + base) = t.u;
}

// ---------------------------------------------------------------------------
// Causal depthwise conv (K=4) + SiLU; bf16 in/out, 8 channels/thread (16B)
// ---------------------------------------------------------------------------
__global__ __launch_bounds__(256)
void conv_silu(const __hip_bfloat16* __restrict__ xz, const float* __restrict__ cw,
               const float* __restrict__ cb, __hip_bfloat16* __restrict__ xb_b)
{
    int idx = blockIdx.x * 256 + threadIdx.x;    // over B*L*(DI/8)
    int d  = (idx & 255) << 3;
    int bl = idx >> 8;
    int l  = bl & (L_ - 1);
    float4 w[8];
    #pragma unroll
    for (int j = 0; j < 8; ++j) w[j] = *(const float4*)(cw + (d + j) * 4);
    float acc[8];
    {
        float4 b0 = *(const float4*)(cb + d);
        float4 b1 = *(const float4*)(cb + d + 4);
        acc[0] = b0.x; acc[1] = b0.y; acc[2] = b0.z; acc[3] = b0.w;
        acc[4] = b1.x; acc[5] = b1.y; acc[6] = b1.z; acc[7] = b1.w;
    }
    #pragma unroll
    for (int k = 0; k < 4; ++k) {
        int lk = l + k - 3;
        if (lk >= 0) {
            union { short8 u; __hip_bfloat16 h[8]; } xu;
            xu.u = *(const short8*)(xz + (size_t)(bl - l + lk) * (2 * DI_) + d);
            #pragma unroll
            for (int j = 0; j < 8; ++j)
                acc[j] += ((const float*)&w[j])[k] * bf2f(xu.h[j]);
        }
    }
    union { __hip_bfloat16 h[8]; short8 u; } t;
    #pragma unroll
    for (int j = 0; j < 8; ++j) {
        float v = acc[j] / (1.f + __expf(-acc[j]));
        t.h[j] = __float2bfloat16(v);
    }
    *(short8*)(xb_b + (size_t)bl * DI_ + d) = t.u;
}

// ---------------------------------------------------------------------------
// SSM pass1: per-chunk local scan from 0 -> decay product Pc, local state Sc
// ---------------------------------------------------------------------------
__global__ __launch_bounds__(256)
void ssm_pass1(const __hip_bfloat16* __restrict__ xb_b,
               const __hip_bfloat16* __restrict__ dlt_b,
               const float* __restrict__ xp, const float* __restrict__ Alog,
               float* __restrict__ Pc, float* __restrict__ Sc)
{
    int blk = blockIdx.x;
    int dgrp = blk & 7, c = (blk >> 3) & 7, b = blk >> 6;
    int d = (dgrp << 8) + threadIdx.x;
    __shared__ float Bsh[CHUNK_][N_];
    for (int i = threadIdx.x; i < CHUNK_ * N_; i += 256) {
        int t = i >> 4, n = i & 15;
        Bsh[t][n] = xp[(size_t)(b * L_ + c * CHUNK_ + t) * XPD_ + DTR_ + n];
    }
    __syncthreads();
    float a[N_], hn[N_], Pn[N_];
    #pragma unroll
    for (int n = 0; n < N_; ++n) {
        a[n] = -__expf(Alog[d * N_ + n]);
        hn[n] = 0.f; Pn[n] = 1.f;
    }
    for (int t = 0; t < CHUNK_; ++t) {
        size_t off = (size_t)(b * L_ + c * CHUNK_ + t) * DI_ + d;
        float dt = bf2f(dlt_b[off]);
        float xv = bf2f(xb_b[off]);
        float dx = dt * xv;
        #pragma unroll
        for (int n = 0; n < N_; ++n) {
            float dA = __expf(dt * a[n]);
            hn[n] = dA * hn[n] + dx * Bsh[t][n];
            Pn[n] *= dA;
        }
    }
    #pragma unroll
    for (int n = 0; n < N_; ++n) {
        size_t o = ((size_t)((b * NC_ + c) * N_ + n)) * DI_ + d;
        Pc[o] = Pn[n]; Sc[o] = hn[n];
    }
}

// ---------------------------------------------------------------------------
// SSM pass2: prefix over earlier chunks (Pc/Sc L2-hot); re-run chunk;
// y = (C.h + x*D) * silu(z) -> bf16
// ---------------------------------------------------------------------------
__global__ __launch_bounds__(256)
void ssm_pass2(const __hip_bfloat16* __restrict__ xb_b,
               const __hip_bfloat16* __restrict__ dlt_b,
               const float* __restrict__ xp, const float* __restrict__ Alog,
               const float* __restrict__ Dp, const __hip_bfloat16* __restrict__ xz,
               const float* __restrict__ Pc, const float* __restrict__ Sc,
               __hip_bfloat16* __restrict__ yout)
{
    int blk = blockIdx.x;
    int dgrp = blk & 7, c = (blk >> 3) & 7, b = blk >> 6;
    int d = (dgrp << 8) + threadIdx.x;
    __shared__ float Bsh[CHUNK_][N_], Csh[CHUNK_][N_];
    for (int i = threadIdx.x; i < CHUNK_ * 2 * N_; i += 256) {
        int t = i >> 5, j = i & 31;
        float v = xp[(size_t)(b * L_ + c * CHUNK_ + t) * XPD_ + DTR_ + j];
        if (j < 16) Bsh[t][j] = v; else Csh[t][j - 16] = v;
    }
    __syncthreads();
    float a[N_], hn[N_];
    #pragma unroll
    for (int n = 0; n < N_; ++n) {
        a[n] = -__expf(Alog[d * N_ + n]);
        hn[n] = 0.f;
    }
    for (int cp = 0; cp < c; ++cp) {
        #pragma unroll
        for (int n = 0; n < N_; ++n) {
            size_t o = ((size_t)((b * NC_ + cp) * N_ + n)) * DI_ + d;
            hn[n] = Pc[o] * hn[n] + Sc[o];
        }
    }
    float dpv = Dp[d];
    for (int t = 0; t < CHUNK_; ++t) {
        int l = c * CHUNK_ + t;
        size_t off = (size_t)(b * L_ + l) * DI_ + d;
        float dt = bf2f(dlt_b[off]);
        float xv = bf2f(xb_b[off]);
        float dx = dt * xv;
        float yv = 0.f;
        #pragma unroll
        for (int n = 0; n < N_; ++n) {
            float dA = __expf(dt * a[n]);
            hn[n] = dA * hn[n] + dx * Bsh[t][n];
            yv += hn[n] * Csh[t][n];
        }
        yv += xv * dpv;
        float z = bf2f(xz[(size_t)(b * L_ + l) * (2 * DI_) + DI_ + d]);
        yout[off] = __float2bfloat16(yv * z / (1.f + __expf(-z)));
    }
}

// ---------------------------------------------------------------------------
// Fused last-layer part-sum + final LayerNorm + head.
// ---------------------------------------------------------------------------
__global__ __launch_bounds__(256)
void head_ln_k(const float* __restrict__ h, const float* __restrict__ parts,
               size_t pstride,
               const float* __restrict__ fw, const float* __restrict__ fb,
               const float* __restrict__ hw, float* __restrict__ out)
{
    __shared__ float red[4][5];
    int b = blockIdx.x / P_;
    int p = blockIdx.x % P_;
    int tid = threadIdx.x;
    size_t rowoff = ((size_t)(b * L_ + L_ - 1)) * DM_ + tid * 4;
    float4 x  = *(const float4*)(h + rowoff);
    float4 p0 = *(const float4*)(parts + rowoff);
    float4 p1 = *(const float4*)(parts + pstride + rowoff);
    x.x += p0.x + p1.x; x.y += p0.y + p1.y;
    x.z += p0.z + p1.z; x.w += p0.w + p1.w;
    float4 w4 = *(const float4*)(fw + tid * 4);
    float4 b4 = *(const float4*)(fb + tid * 4);
    float4 g4 = *(const float4*)(hw + (size_t)p * DM_ + tid * 4);
    float s  = x.x + x.y + x.z + x.w;
    float s2 = x.x * x.x + x.y * x.y + x.z * x.z + x.w * x.w;
    float t1 = x.x * w4.x * g4.x + x.y * w4.y * g4.y + x.z * w4.z * g4.z + x.w * w4.w * g4.w;
    float t2 = w4.x * g4.x + w4.y * g4.y + w4.z * g4.z + w4.w * g4.w;
    float t3 = b4.x * g4.x + b4.y * g4.y + b4.z * g4.z + b4.w * g4.w;
    #pragma unroll
    for (int o = 32; o > 0; o >>= 1) {
        s  += __shfl_down(s, o);
        s2 += __shfl_down(s2, o);
        t1 += __shfl_down(t1, o);
        t2 += __shfl_down(t2, o);
        t3 += __shfl_down(t3, o);
    }
    if ((tid & 63) == 0) {
        int w = tid >> 6;
        red[w][0] = s; red[w][1] = s2; red[w][2] = t1; red[w][3] = t2; red[w][4] = t3;
    }
    __syncthreads();
    if (tid == 0) {
        float st  = red[0][0] + red[1][0] + red[2][0] + red[3][0];
        float s2t = red[0][1] + red[1][1] + red[2][1] + red[3][1];
        float t1t = red[0][2] + red[1][2] + red[2][2] + red[3][2];
        float t2t = red[0][3] + red[1][3] + red[2][3] + red[3][3];
        float t3t = red[0][4] + red[1][4] + red[2][4] + red[3][4];
        float m   = st * (1.f / DM_);
        float var = s2t * (1.f / DM_) - m * m;
        float rs  = rsqrtf(var + 1e-5f);
        out[blockIdx.x] = rs * (t1t - m * t2t) + t3t;
    }
}

// ---------------------------------------------------------------------------
extern "C" void kernel_launch(void* const* d_in, const int* in_sizes, int n_in,
                              void* d_out, int out_size, void* d_ws, size_t ws_size,
                              hipStream_t stream)
{
    const int*   tokens     = (const int*)  d_in[0];
    const float* tok_emb    = (const float*)d_in[1];
    const float* pos_emb    = (const float*)d_in[2];
    const float* ln_w       = (const float*)d_in[3];
    const float* ln_b       = (const float*)d_in[4];
    const float* in_proj_w  = (const float*)d_in[5];
    const float* conv_w     = (const float*)d_in[6];
    const float* conv_b     = (const float*)d_in[7];
    const float* xproj_w    = (const float*)d_in[8];
    const float* dt_w       = (const float*)d_in[9];
    const float* dt_b       = (const float*)d_in[10];
    const float* A_log      = (const float*)d_in[11];
    const float* D_param    = (const float*)d_in[12];
    const float* out_proj_w = (const float*)d_in[13];
    const float* fnorm_w    = (const float*)d_in[14];
    const float* fnorm_b    = (const float*)d_in[15];
    const float* head_w     = (const float*)d_in[16];
    float* out = (float*)d_out;
    float* ws  = (float*)d_ws;

    // fp32 workspace (floats)
    float* h      = ws;                   // B*L*DM    = 2,097,152
    float* xp     = h    + 2097152;       // B*L*XPD   =   327,680
    float* Pc     = xp   + 327680;        // B*NC*N*DI = 2,097,152
    float* Sc     = Pc   + 2097152;       // 2,097,152
    float* part_h = Sc   + 2097152;       // 2 x B*L*DM = 4,194,304
    // bf16 workspace
    __hip_bfloat16* bfb = (__hip_bfloat16*)(part_h + 4194304);
    __hip_bfloat16* xz_b  = bfb;                 // B*L*2DI = 8,388,608 el
    __hip_bfloat16* xln_b = xz_b  + 8388608;     // B*L*DM  = 2,097,152 el
    __hip_bfloat16* y_b   = xln_b + 2097152;     // B*L*DI  = 4,194,304 el
    __hip_bfloat16* xb_b  = y_b   + 4194304;     // B*L*DI  = 4,194,304 el
    __hip_bfloat16* dlt_b = xb_b  + 4194304;     // B*L*DI  = 4,194,304 el
    __hip_bfloat16* xp_b  = dlt_b + 4194304;     // B*L*XPD =   327,680 el
    // split-K partials for xproj alias Pc+Sc (dead until ssm_pass1)
    float* part_xp = Pc;   // 8 x 2048 x 160 = 2,621,440 fl <= 4,194,304 fl

    // ---- embedding + layer-0 LN
    embed_ln_k<<<B_ * L_, 256, 0, stream>>>(tokens, tok_emb, pos_emb,
                                            ln_w, ln_b, h, xln_b);

    for (int li = 0; li < NL_; ++li) {
        // xz = x @ in_proj_w^T  (2048 x 4096, K=1024) -> bf16 [TN=64]
        gemm_wf32<0, 64><<<dim3(2 * DI_ / 64, B_ * L_ / 128), 256, 0, stream>>>(
            xln_b, DM_, in_proj_w + (size_t)li * 2 * DI_ * DM_, DM_,
            xz_b, 2 * DI_, DM_, 0, nullptr);

        // x_branch = silu(conv(xz[...,:DI]))  -> bf16 (8 ch/thread)
        conv_silu<<<B_ * L_ * DI_ / 8 / 256, 256, 0, stream>>>(
            xz_b, conv_w + li * DI_ * K_, conv_b + li * DI_, xb_b);

        // xp = x_branch @ xproj_w^T  (2048 x 160, K=2048) [TN=128 splitK-8]
        gemm_wf32<3, 128><<<dim3(2, B_ * L_ / 128, 8), 256, 0, stream>>>(
            xb_b, DI_, xproj_w + (size_t)li * XPD_ * DI_, DI_,
            part_xp, XPD_, DI_ / 8, XPD_, nullptr);
        reduce_xp_k<8><<<B_ * L_ * XPD_ / 1024, 256, 0, stream>>>(
            part_xp, xp, xp_b, (size_t)B_ * L_ * XPD_);

        // delta = softplus(dt_r @ dt_w^T + dt_b) (2048x2048, K=128) [TN=64]
        gemm_wf32<5, 64><<<dim3(DI_ / 64, B_ * L_ / 128), 256, 0, stream>>>(
            xp_b, XPD_, dt_w + (size_t)li * DI_ * DTR_, DTR_,
            dlt_b, DI_, DTR_, 0, dt_b + li * DI_);

        // chunked selective scan
        ssm_pass1<<<B_ * NC_ * (DI_ / 256), 256, 0, stream>>>(
            xb_b, dlt_b, xp, A_log + li * DI_ * N_, Pc, Sc);
        ssm_pass2<<<B_ * NC_ * (DI_ / 256), 256, 0, stream>>>(
            xb_b, dlt_b, xp, A_log + li * DI_ * N_, D_param + li * DI_,
            xz_b, Pc, Sc, y_b);

        // h += y @ out_proj_w^T  (2048 x 1024, K=2048) [TN=64 splitK-2]
        gemm_wf32<2, 64><<<dim3(DM_ / 64, B_ * L_ / 128, 2), 256, 0, stream>>>(
            y_b, DI_, out_proj_w + (size_t)li * DM_ * DI_, DI_,
            part_h, DM_, DI_ / 2, 0, nullptr);

        if (li < NL_ - 1) {
            reduce_ln_k<2><<<B_ * L_, 256, 0, stream>>>(
                part_h, h, ln_w + (li + 1) * DM_, ln_b + (li + 1) * DM_,
                xln_b, (size_t)B_ * L_ * DM_);
        }
    }

    // fused last-layer residual + final LN + head
    head_ln_k<<<B_ * P_, 256, 0, stream>>>(
        h, part_h, (size_t)B_ * L_ * DM_, fnorm_w, fnorm_b, head_w, out);
}

// Round 9
// 835.664 us; speedup vs baseline: 1.0929x; 1.0929x over previous
//
#include <hip/hip_runtime.h>
#include <hip/hip_bf16.h>
#include <cstdint>
#include <cstddef>

#define B_    8
#define L_    256
#define DM_   1024
#define DI_   2048
#define N_    16
#define K_    4
#define NL_   4
#define DTR_  128
#define P_    97
#define XPD_  160   // DTR + 2N
#define CHUNK_ 32
#define NC_   8     // L / CHUNK

typedef __attribute__((ext_vector_type(8))) short short8;
typedef __attribute__((ext_vector_type(4))) float floatx4;

__device__ __forceinline__ void async16(const void* g, void* l)
{
    __builtin_amdgcn_global_load_lds(
        (const __attribute__((address_space(1))) void*)g,
        (__attribute__((address_space(3))) void*)l,
        16, 0, 0);
}

__device__ __forceinline__ float bf2f(__hip_bfloat16 h) { return __bfloat162float(h); }

__device__ __forceinline__ void cvt8v(float4 a, float4 b, __hip_bfloat16* d)
{
    union { __hip_bfloat16 h[8]; short8 u; } t;
    t.h[0] = __float2bfloat16(a.x); t.h[1] = __float2bfloat16(a.y);
    t.h[2] = __float2bfloat16(a.z); t.h[3] = __float2bfloat16(a.w);
    t.h[4] = __float2bfloat16(b.x); t.h[5] = __float2bfloat16(b.y);
    t.h[6] = __float2bfloat16(b.z); t.h[7] = __float2bfloat16(b.w);
    *(short8*)d = t.u;
}

// ---------------------------------------------------------------------------
// Fused weight conversion (32 el/thread, 8 indep float4 loads in flight)
// + embedding+LN0 (extra blocks).
// Conversion blocks each cover 8192 contiguous elems, thread t handles 4
// groups of 8 at offsets t*8 + g*2048 (wave reads 2KB contiguous per group).
// blocks: [0,2048) ipw | [2048,3072) opw | [3072,3200) dtw |
//         [3200,3456) xpw(padded 256 rows) | [3456,5504) embed+LN rows
// ---------------------------------------------------------------------------
__global__ __launch_bounds__(256)
void wconv_embed_k(const float* __restrict__ ipw, const float* __restrict__ opw,
                   const float* __restrict__ dtw, const float* __restrict__ xpw,
                   __hip_bfloat16* __restrict__ ipb, __hip_bfloat16* __restrict__ opb,
                   __hip_bfloat16* __restrict__ dtb, __hip_bfloat16* __restrict__ xpb,
                   const int* __restrict__ tokens, const float* __restrict__ te,
                   const float* __restrict__ pe, const float* __restrict__ lw,
                   const float* __restrict__ lb, float* __restrict__ h,
                   __hip_bfloat16* __restrict__ xout)
{
    __shared__ float red[8];
    int blk = blockIdx.x;
    int tid = threadIdx.x;
    if (blk < 3456) {
        const float* src; __hip_bfloat16* dst; size_t base; bool xpad = false;
        if (blk < 2048)      { src = ipw; dst = ipb; base = (size_t)blk * 8192; }
        else if (blk < 3072) { src = opw; dst = opb; base = (size_t)(blk - 2048) * 8192; }
        else if (blk < 3200) { src = dtw; dst = dtb; base = (size_t)(blk - 3072) * 8192; }
        else                 { src = xpw; dst = xpb; base = (size_t)(blk - 3200) * 8192; xpad = true; }
        float4 v[8];
        size_t off[4];
        #pragma unroll
        for (int g = 0; g < 4; ++g) {
            size_t i = base + (size_t)g * 2048 + tid * 8;
            off[g] = i;
            if (!xpad) {
                v[2*g]   = *(const float4*)(src + i);
                v[2*g+1] = *(const float4*)(src + i + 4);
            } else {
                int col   = (int)(i & 2047);
                int row   = (int)((i >> 11) & 255);
                int layer = (int)(i >> 19);
                if (row < XPD_) {
                    const float* s = src + ((size_t)layer * XPD_ + row) * 2048 + col;
                    v[2*g]   = *(const float4*)s;
                    v[2*g+1] = *(const float4*)(s + 4);
                } else {
                    v[2*g] = v[2*g+1] = make_float4(0.f, 0.f, 0.f, 0.f);
                }
            }
        }
        #pragma unroll
        for (int g = 0; g < 4; ++g)
            cvt8v(v[2*g], v[2*g+1], dst + off[g]);
        return;
    }
    // ---- embedding + layer-0 LN
    int bl = blk - 3456;
    int l  = bl & (L_ - 1);
    int tok = tokens[bl];
    float4 a = *(const float4*)(te + (size_t)tok * DM_ + tid * 4);
    float4 p = *(const float4*)(pe + (size_t)l * DM_ + tid * 4);
    float4 x = make_float4(a.x + p.x, a.y + p.y, a.z + p.z, a.w + p.w);
    size_t base = (size_t)bl * DM_ + tid * 4;
    *(float4*)(h + base) = x;

    float s  = x.x + x.y + x.z + x.w;
    float s2 = x.x * x.x + x.y * x.y + x.z * x.z + x.w * x.w;
    #pragma unroll
    for (int o = 32; o > 0; o >>= 1) {
        s  += __shfl_down(s, o);
        s2 += __shfl_down(s2, o);
    }
    if ((tid & 63) == 0) { red[tid >> 6] = s; red[4 + (tid >> 6)] = s2; }
    __syncthreads();
    float st  = red[0] + red[1] + red[2] + red[3];
    float s2t = red[4] + red[5] + red[6] + red[7];
    float m   = st * (1.f / DM_);
    float var = s2t * (1.f / DM_) - m * m;
    float rs  = rsqrtf(var + 1e-5f);
    float4 wv = *(const float4*)(lw + tid * 4);
    float4 bv = *(const float4*)(lb + tid * 4);
    union { __hip_bfloat16 h[4]; ushort4 u; } t;
    t.h[0] = __float2bfloat16((x.x - m) * rs * wv.x + bv.x);
    t.h[1] = __float2bfloat16((x.y - m) * rs * wv.y + bv.y);
    t.h[2] = __float2bfloat16((x.z - m) * rs * wv.z + bv.z);
    t.h[3] = __float2bfloat16((x.w - m) * rs * wv.w + bv.w);
    *(ushort4*)(xout + base) = t.u;
}

// ---------------------------------------------------------------------------
// bf16 MFMA GEMM, 128xTN tile (TN = 128 or 64), BK=32, global_load_lds w16.
// MODE 0: full-K -> bf16 C
// MODE 2: split-K partial -> fp32 Cp[z][M][ldc]
// MODE 3: split-K partial fp32 with epilogue col<Nb guard (B rows pre-padded)
// MODE 5: full-K, bias+softplus -> bf16 C (dt matmul)
// ---------------------------------------------------------------------------
template<int MODE, int TN>
__global__ __launch_bounds__(256)
void gemm_bf16(const __hip_bfloat16* __restrict__ A, int lda,
               const __hip_bfloat16* __restrict__ Bw, int ldb,
               void* __restrict__ Cv, int ldc, int Kp, int Nb,
               const float* __restrict__ bias)
{
    constexpr int JW = (TN == 128) ? 4 : 2;
    __shared__ __hip_bfloat16 As[128 * 32];
    __shared__ __hip_bfloat16 Bs[TN * 32];
    const int tid  = threadIdx.x;
    const int lane = tid & 63;
    const int wid  = tid >> 6;
    const int wm   = wid >> 1, wn = wid & 1;
    const int mbase = blockIdx.y * 128;
    const int nbase = blockIdx.x * TN;
    const int koff  = (MODE == 2 || MODE == 3) ? blockIdx.z * Kp : 0;

    floatx4 acc[4][JW] = {};

    const int f0 = tid * 16;
    const int r0 = f0 >> 6, c0 = f0 & 63;
    const int f1 = f0 + 4096;
    const int r1 = f1 >> 6, c1 = f1 & 63;

    const int fr = lane & 15;
    const int kq = (lane >> 4) * 8;

    for (int k0 = koff; k0 < koff + Kp; k0 += 32) {
        const char* Ag = (const char*)(A + (size_t)mbase * lda + k0);
        const char* Bg = (const char*)(Bw + (size_t)nbase * ldb + k0);
        async16(Ag + (size_t)r0 * lda * 2 + c0, (char*)As + f0);
        async16(Ag + (size_t)r1 * lda * 2 + c1, (char*)As + f1);
        async16(Bg + (size_t)r0 * ldb * 2 + c0, (char*)Bs + f0);
        if constexpr (TN == 128)
            async16(Bg + (size_t)r1 * ldb * 2 + c1, (char*)Bs + f1);
        __syncthreads();

        short8 af[4], bf[JW];
        #pragma unroll
        for (int i = 0; i < 4; ++i) {
            int m = wm * 64 + i * 16 + fr;
            af[i] = *(const short8*)(As + m * 32 + kq);
        }
        #pragma unroll
        for (int j = 0; j < JW; ++j) {
            int n = wn * (TN / 2) + j * 16 + fr;
            bf[j] = *(const short8*)(Bs + n * 32 + kq);
        }
        #pragma unroll
        for (int i = 0; i < 4; ++i)
            #pragma unroll
            for (int j = 0; j < JW; ++j)
                acc[i][j] = __builtin_amdgcn_mfma_f32_16x16x32_bf16(
                    af[i], bf[j], acc[i][j], 0, 0, 0);
        __syncthreads();
    }

    const int cq = lane >> 4;
    float* Cf = (float*)Cv;
    __hip_bfloat16* Ch = (__hip_bfloat16*)Cv;
    size_t zoff = (MODE == 2 || MODE == 3)
                ? (size_t)blockIdx.z * (gridDim.y * 128) * ldc : 0;
    #pragma unroll
    for (int i = 0; i < 4; ++i) {
        #pragma unroll
        for (int j = 0; j < JW; ++j) {
            int col = nbase + wn * (TN / 2) + j * 16 + fr;
            if (MODE == 3 && col >= Nb) continue;
            float bv = (MODE == 5) ? bias[col] : 0.f;
            #pragma unroll
            for (int r = 0; r < 4; ++r) {
                int row = mbase + wm * 64 + i * 16 + cq * 4 + r;
                float v = acc[i][j][r];
                size_t off = zoff + (size_t)row * ldc + col;
                if (MODE == 2 || MODE == 3) {
                    Cf[off] = v;
                } else if (MODE == 5) {
                    v += bv;
                    v = (v > 20.f) ? v : log1pf(__expf(v));
                    Ch[off] = __float2bfloat16(v);
                } else {
                    Ch[off] = __float2bfloat16(v);
                }
            }
        }
    }
}

// ---------------------------------------------------------------------------
// Split-K reduce for xp: emit fp32 xp AND bf16 xp_b
// ---------------------------------------------------------------------------
template<int PARTS>
__global__ __launch_bounds__(256)
void reduce_xp_k(const float* __restrict__ p, float* __restrict__ dst,
                 __hip_bfloat16* __restrict__ dst_b, size_t stride)
{
    size_t i = ((size_t)blockIdx.x * 256 + threadIdx.x) * 4;
    float4 s = *(const float4*)(p + i);
    #pragma unroll
    for (int z = 1; z < PARTS; ++z) {
        float4 v = *(const float4*)(p + z * stride + i);
        s.x += v.x; s.y += v.y; s.z += v.z; s.w += v.w;
    }
    *(float4*)(dst + i) = s;
    union { __hip_bfloat16 h[4]; ushort4 u; } t;
    t.h[0] = __float2bfloat16(s.x);
    t.h[1] = __float2bfloat16(s.y);
    t.h[2] = __float2bfloat16(s.z);
    t.h[3] = __float2bfloat16(s.w);
    *(ushort4*)(dst_b + i) = t.u;
}

// ---------------------------------------------------------------------------
// Fused: h[row] += sum_z part[z][row]; then LayerNorm(h[row]) -> bf16 out.
// ---------------------------------------------------------------------------
template<int PARTS>
__global__ __launch_bounds__(256)
void reduce_ln_k(const float* __restrict__ p, float* __restrict__ h,
                 const float* __restrict__ w, const float* __restrict__ b,
                 __hip_bfloat16* __restrict__ out, size_t stride)
{
    __shared__ float red[8];
    int tid = threadIdx.x;
    size_t base = (size_t)blockIdx.x * DM_ + tid * 4;
    float4 x = *(const float4*)(h + base);
    #pragma unroll
    for (int z = 0; z < PARTS; ++z) {
        float4 v = *(const float4*)(p + z * stride + base);
        x.x += v.x; x.y += v.y; x.z += v.z; x.w += v.w;
    }
    *(float4*)(h + base) = x;

    float s  = x.x + x.y + x.z + x.w;
    float s2 = x.x * x.x + x.y * x.y + x.z * x.z + x.w * x.w;
    #pragma unroll
    for (int o = 32; o > 0; o >>= 1) {
        s  += __shfl_down(s, o);
        s2 += __shfl_down(s2, o);
    }
    if ((tid & 63) == 0) { red[tid >> 6] = s; red[4 + (tid >> 6)] = s2; }
    __syncthreads();
    float st  = red[0] + red[1] + red[2] + red[3];
    float s2t = red[4] + red[5] + red[6] + red[7];
    float m   = st * (1.f / DM_);
    float var = s2t * (1.f / DM_) - m * m;
    float rs  = rsqrtf(var + 1e-5f);
    float4 wv = *(const float4*)(w + tid * 4);
    float4 bv = *(const float4*)(b + tid * 4);
    union { __hip_bfloat16 h[4]; ushort4 u; } t;
    t.h[0] = __float2bfloat16((x.x - m) * rs * wv.x + bv.x);
    t.h[1] = __float2bfloat16((x.y - m) * rs * wv.y + bv.y);
    t.h[2] = __float2bfloat16((x.z - m) * rs * wv.z + bv.z);
    t.h[3] = __float2bfloat16((x.w - m) * rs * wv.w + bv.w);
    *(ushort4*)(out + base) = t.u;
}

// ---------------------------------------------------------------------------
// Causal depthwise conv (K=4) + SiLU; bf16 in/out, 8 channels/thread (16B)
// ---------------------------------------------------------------------------
__global__ __launch_bounds__(256)
void conv_silu(const __hip_bfloat16* __restrict__ xz, const float* __restrict__ cw,
               const float* __restrict__ cb, __hip_bfloat16* __restrict__ xb_b)
{
    int idx = blockIdx.x * 256 + threadIdx.x;    // over B*L*(DI/8)
    int d  = (idx & 255) << 3;
    int bl = idx >> 8;
    int l  = bl & (L_ - 1);
    float4 w[8];
    #pragma unroll
    for (int j = 0; j < 8; ++j) w[j] = *(const float4*)(cw + (d + j) * 4);
    float acc[8];
    {
        float4 b0 = *(const float4*)(cb + d);
        float4 b1 = *(const float4*)(cb + d + 4);
        acc[0] = b0.x; acc[1] = b0.y; acc[2] = b0.z; acc[3] = b0.w;
        acc[4] = b1.x; acc[5] = b1.y; acc[6] = b1.z; acc[7] = b1.w;
    }
    #pragma unroll
    for (int k = 0; k < 4; ++k) {
        int lk = l + k - 3;
        if (lk >= 0) {
            union { short8 u; __hip_bfloat16 h[8]; } xu;
            xu.u = *(const short8*)(xz + (size_t)(bl - l + lk) * (2 * DI_) + d);
            #pragma unroll
            for (int j = 0; j < 8; ++j)
                acc[j] += ((const float*)&w[j])[k] * bf2f(xu.h[j]);
        }
    }
    union { __hip_bfloat16 h[8]; short8 u; } t;
    #pragma unroll
    for (int j = 0; j < 8; ++j) {
        float v = acc[j] / (1.f + __expf(-acc[j]));
        t.h[j] = __float2bfloat16(v);
    }
    *(short8*)(xb_b + (size_t)bl * DI_ + d) = t.u;
}

// ---------------------------------------------------------------------------
// SSM pass1: per-chunk local scan from 0 -> decay product Pc, local state Sc
// ---------------------------------------------------------------------------
__global__ __launch_bounds__(256)
void ssm_pass1(const __hip_bfloat16* __restrict__ xb_b,
               const __hip_bfloat16* __restrict__ dlt_b,
               const float* __restrict__ xp, const float* __restrict__ Alog,
               float* __restrict__ Pc, float* __restrict__ Sc)
{
    int blk = blockIdx.x;
    int dgrp = blk & 7, c = (blk >> 3) & 7, b = blk >> 6;
    int d = (dgrp << 8) + threadIdx.x;
    __shared__ float Bsh[CHUNK_][N_];
    for (int i = threadIdx.x; i < CHUNK_ * N_; i += 256) {
        int t = i >> 4, n = i & 15;
        Bsh[t][n] = xp[(size_t)(b * L_ + c * CHUNK_ + t) * XPD_ + DTR_ + n];
    }
    __syncthreads();
    float a[N_], hn[N_], Pn[N_];
    #pragma unroll
    for (int n = 0; n < N_; ++n) {
        a[n] = -__expf(Alog[d * N_ + n]);
        hn[n] = 0.f; Pn[n] = 1.f;
    }
    for (int t = 0; t < CHUNK_; ++t) {
        size_t off = (size_t)(b * L_ + c * CHUNK_ + t) * DI_ + d;
        float dt = bf2f(dlt_b[off]);
        float xv = bf2f(xb_b[off]);
        float dx = dt * xv;
        #pragma unroll
        for (int n = 0; n < N_; ++n) {
            float dA = __expf(dt * a[n]);
            hn[n] = dA * hn[n] + dx * Bsh[t][n];
            Pn[n] *= dA;
        }
    }
    #pragma unroll
    for (int n = 0; n < N_; ++n) {
        size_t o = ((size_t)((b * NC_ + c) * N_ + n)) * DI_ + d;
        Pc[o] = Pn[n]; Sc[o] = hn[n];
    }
}

// ---------------------------------------------------------------------------
// SSM pass2: prefix over earlier chunks (Pc/Sc L2-hot); re-run chunk;
// y = (C.h + x*D) * silu(z) -> bf16
// ---------------------------------------------------------------------------
__global__ __launch_bounds__(256)
void ssm_pass2(const __hip_bfloat16* __restrict__ xb_b,
               const __hip_bfloat16* __restrict__ dlt_b,
               const float* __restrict__ xp, const float* __restrict__ Alog,
               const float* __restrict__ Dp, const __hip_bfloat16* __restrict__ xz,
               const float* __restrict__ Pc, const float* __restrict__ Sc,
               __hip_bfloat16* __restrict__ yout)
{
    int blk = blockIdx.x;
    int dgrp = blk & 7, c = (blk >> 3) & 7, b = blk >> 6;
    int d = (dgrp << 8) + threadIdx.x;
    __shared__ float Bsh[CHUNK_][N_], Csh[CHUNK_][N_];
    for (int i = threadIdx.x; i < CHUNK_ * 2 * N_; i += 256) {
        int t = i >> 5, j = i & 31;
        float v = xp[(size_t)(b * L_ + c * CHUNK_ + t) * XPD_ + DTR_ + j];
        if (j < 16) Bsh[t][j] = v; else Csh[t][j - 16] = v;
    }
    __syncthreads();
    float a[N_], hn[N_];
    #pragma unroll
    for (int n = 0; n < N_; ++n) {
        a[n] = -__expf(Alog[d * N_ + n]);
        hn[n] = 0.f;
    }
    for (int cp = 0; cp < c; ++cp) {
        #pragma unroll
        for (int n = 0; n < N_; ++n) {
            size_t o = ((size_t)((b * NC_ + cp) * N_ + n)) * DI_ + d;
            hn[n] = Pc[o] * hn[n] + Sc[o];
        }
    }
    float dpv = Dp[d];
    for (int t = 0; t < CHUNK_; ++t) {
        int l = c * CHUNK_ + t;
        size_t off = (size_t)(b * L_ + l) * DI_ + d;
        float dt = bf2f(dlt_b[off]);
        float xv = bf2f(xb_b[off]);
        float dx = dt * xv;
        float yv = 0.f;
        #pragma unroll
        for (int n = 0; n < N_; ++n) {
            float dA = __expf(dt * a[n]);
            hn[n] = dA * hn[n] + dx * Bsh[t][n];
            yv += hn[n] * Csh[t][n];
        }
        yv += xv * dpv;
        float z = bf2f(xz[(size_t)(b * L_ + l) * (2 * DI_) + DI_ + d]);
        yout[off] = __float2bfloat16(yv * z / (1.f + __expf(-z)));
    }
}

// ---------------------------------------------------------------------------
// Fused last-layer part-sum + final LayerNorm + head.
// ---------------------------------------------------------------------------
__global__ __launch_bounds__(256)
void head_ln_k(const float* __restrict__ h, const float* __restrict__ parts,
               size_t pstride,
               const float* __restrict__ fw, const float* __restrict__ fb,
               const float* __restrict__ hw, float* __restrict__ out)
{
    __shared__ float red[4][5];
    int b = blockIdx.x / P_;
    int p = blockIdx.x % P_;
    int tid = threadIdx.x;
    size_t rowoff = ((size_t)(b * L_ + L_ - 1)) * DM_ + tid * 4;
    float4 x  = *(const float4*)(h + rowoff);
    float4 p0 = *(const float4*)(parts + rowoff);
    float4 p1 = *(const float4*)(parts + pstride + rowoff);
    x.x += p0.x + p1.x; x.y += p0.y + p1.y;
    x.z += p0.z + p1.z; x.w += p0.w + p1.w;
    float4 w4 = *(const float4*)(fw + tid * 4);
    float4 b4 = *(const float4*)(fb + tid * 4);
    float4 g4 = *(const float4*)(hw + (size_t)p * DM_ + tid * 4);
    float s  = x.x + x.y + x.z + x.w;
    float s2 = x.x * x.x + x.y * x.y + x.z * x.z + x.w * x.w;
    float t1 = x.x * w4.x * g4.x + x.y * w4.y * g4.y + x.z * w4.z * g4.z + x.w * w4.w * g4.w;
    float t2 = w4.x * g4.x + w4.y * g4.y + w4.z * g4.z + w4.w * g4.w;
    float t3 = b4.x * g4.x + b4.y * g4.y + b4.z * g4.z + b4.w * g4.w;
    #pragma unroll
    for (int o = 32; o > 0; o >>= 1) {
        s  += __shfl_down(s, o);
        s2 += __shfl_down(s2, o);
        t1 += __shfl_down(t1, o);
        t2 += __shfl_down(t2, o);
        t3 += __shfl_down(t3, o);
    }
    if ((tid & 63) == 0) {
        int w = tid >> 6;
        red[w][0] = s; red[w][1] = s2; red[w][2] = t1; red[w][3] = t2; red[w][4] = t3;
    }
    __syncthreads();
    if (tid == 0) {
        float st  = red[0][0] + red[1][0] + red[2][0] + red[3][0];
        float s2t = red[0][1] + red[1][1] + red[2][1] + red[3][1];
        float t1t = red[0][2] + red[1][2] + red[2][2] + red[3][2];
        float t2t = red[0][3] + red[1][3] + red[2][3] + red[3][3];
        float t3t = red[0][4] + red[1][4] + red[2][4] + red[3][4];
        float m   = st * (1.f / DM_);
        float var = s2t * (1.f / DM_) - m * m;
        float rs  = rsqrtf(var + 1e-5f);
        out[blockIdx.x] = rs * (t1t - m * t2t) + t3t;
    }
}

// ---------------------------------------------------------------------------
extern "C" void kernel_launch(void* const* d_in, const int* in_sizes, int n_in,
                              void* d_out, int out_size, void* d_ws, size_t ws_size,
                              hipStream_t stream)
{
    const int*   tokens     = (const int*)  d_in[0];
    const float* tok_emb    = (const float*)d_in[1];
    const float* pos_emb    = (const float*)d_in[2];
    const float* ln_w       = (const float*)d_in[3];
    const float* ln_b       = (const float*)d_in[4];
    const float* in_proj_w  = (const float*)d_in[5];
    const float* conv_w     = (const float*)d_in[6];
    const float* conv_b     = (const float*)d_in[7];
    const float* xproj_w    = (const float*)d_in[8];
    const float* dt_w       = (const float*)d_in[9];
    const float* dt_b       = (const float*)d_in[10];
    const float* A_log      = (const float*)d_in[11];
    const float* D_param    = (const float*)d_in[12];
    const float* out_proj_w = (const float*)d_in[13];
    const float* fnorm_w    = (const float*)d_in[14];
    const float* fnorm_b    = (const float*)d_in[15];
    const float* head_w     = (const float*)d_in[16];
    float* out = (float*)d_out;
    float* ws  = (float*)d_ws;

    // fp32 workspace (floats)
    float* h      = ws;                   // B*L*DM    = 2,097,152
    float* xp     = h    + 2097152;       // B*L*XPD   =   327,680
    float* Pc     = xp   + 327680;        // B*NC*N*DI = 2,097,152
    float* Sc     = Pc   + 2097152;       // 2,097,152
    float* part_h = Sc   + 2097152;       // 2 x B*L*DM = 4,194,304
    // bf16 workspace
    __hip_bfloat16* bfb = (__hip_bfloat16*)(part_h + 4194304);
    __hip_bfloat16* xz_b  = bfb;                 // B*L*2DI = 8,388,608 el
    __hip_bfloat16* xln_b = xz_b  + 8388608;     // B*L*DM  = 2,097,152 el
    __hip_bfloat16* y_b   = xln_b + 2097152;     // B*L*DI  = 4,194,304 el
    __hip_bfloat16* xb_b  = y_b   + 4194304;     // B*L*DI  = 4,194,304 el
    __hip_bfloat16* dlt_b = xb_b  + 4194304;     // B*L*DI  = 4,194,304 el
    __hip_bfloat16* xp_b  = dlt_b + 4194304;     // B*L*XPD =   327,680 el
    __hip_bfloat16* dtw_b = xp_b  + 327680;      // NL*DI*DTR = 1,048,576 el
    __hip_bfloat16* ipw_b = dtw_b + 1048576;     // NL*2DI*DM = 16,777,216 el
    __hip_bfloat16* opw_b = ipw_b + 16777216;    // NL*DM*DI  =  8,388,608 el
    __hip_bfloat16* xpw_b = opw_b + 8388608;     // NL*256*2048 = 2,097,152 el
    // split-K partials for xproj alias Pc+Sc (dead until ssm_pass1)
    float* part_xp = Pc;   // 8 x 2048 x 160 = 2,621,440 fl <= 4,194,304 fl

    // ---- weights -> bf16 (32 el/thread) + embedding + layer-0 LN
    wconv_embed_k<<<3456 + B_ * L_, 256, 0, stream>>>(
        in_proj_w, out_proj_w, dt_w, xproj_w, ipw_b, opw_b, dtw_b, xpw_b,
        tokens, tok_emb, pos_emb, ln_w, ln_b, h, xln_b);

    for (int li = 0; li < NL_; ++li) {
        // xz = x @ in_proj_w^T  (2048 x 4096, K=1024) -> bf16 [TN=64]
        gemm_bf16<0, 64><<<dim3(2 * DI_ / 64, B_ * L_ / 128), 256, 0, stream>>>(
            xln_b, DM_, ipw_b + (size_t)li * 2 * DI_ * DM_, DM_,
            xz_b, 2 * DI_, DM_, 0, nullptr);

        // x_branch = silu(conv(xz[...,:DI]))  -> bf16 (8 ch/thread)
        conv_silu<<<B_ * L_ * DI_ / 8 / 256, 256, 0, stream>>>(
            xz_b, conv_w + li * DI_ * K_, conv_b + li * DI_, xb_b);

        // xp = x_branch @ xproj_w^T  (2048 x 160, K=2048) [TN=128 splitK-8]
        gemm_bf16<3, 128><<<dim3(2, B_ * L_ / 128, 8), 256, 0, stream>>>(
            xb_b, DI_, xpw_b + (size_t)li * 256 * 2048, DI_,
            part_xp, XPD_, DI_ / 8, XPD_, nullptr);
        reduce_xp_k<8><<<B_ * L_ * XPD_ / 1024, 256, 0, stream>>>(
            part_xp, xp, xp_b, (size_t)B_ * L_ * XPD_);

        // delta = softplus(dt_r @ dt_w^T + dt_b) (2048x2048, K=128) [TN=64]
        gemm_bf16<5, 64><<<dim3(DI_ / 64, B_ * L_ / 128), 256, 0, stream>>>(
            xp_b, XPD_, dtw_b + (size_t)li * DI_ * DTR_, DTR_,
            dlt_b, DI_, DTR_, 0, dt_b + li * DI_);

        // chunked selective scan
        ssm_pass1<<<B_ * NC_ * (DI_ / 256), 256, 0, stream>>>(
            xb_b, dlt_b, xp, A_log + li * DI_ * N_, Pc, Sc);
        ssm_pass2<<<B_ * NC_ * (DI_ / 256), 256, 0, stream>>>(
            xb_b, dlt_b, xp, A_log + li * DI_ * N_, D_param + li * DI_,
            xz_b, Pc, Sc, y_b);

        // h += y @ out_proj_w^T  (2048 x 1024, K=2048) [TN=64 splitK-2]
        gemm_bf16<2, 64><<<dim3(DM_ / 64, B_ * L_ / 128, 2), 256, 0, stream>>>(
            y_b, DI_, opw_b + (size_t)li * DM_ * DI_, DI_,
            part_h, DM_, DI_ / 2, 0, nullptr);

        if (li < NL_ - 1) {
            reduce_ln_k<2><<<B_ * L_, 256, 0, stream>>>(
                part_h, h, ln_w + (li + 1) * DM_, ln_b + (li + 1) * DM_,
                xln_b, (size_t)B_ * L_ * DM_);
        }
    }

    // fused last-layer residual + final LN + head
    head_ln_k<<<B_ * P_, 256, 0, stream>>>(
        h, part_h, (size_t)B_ * L_ * DM_, fnorm_w, fnorm_b, head_w, out);
}

// Round 10
// 814.087 us; speedup vs baseline: 1.1218x; 1.0265x over previous
//
#include <hip/hip_runtime.h>
#include <hip/hip_bf16.h>
#include <cstdint>
#include <cstddef>

#define B_    8
#define L_    256
#define DM_   1024
#define DI_   2048
#define N_    16
#define K_    4
#define NL_   4
#define DTR_  128
#define P_    97
#define XPD_  160   // DTR + 2N
#define CHUNK_ 32
#define NC_   8     // L / CHUNK

typedef __attribute__((ext_vector_type(8))) short short8;
typedef __attribute__((ext_vector_type(4))) float floatx4;

__device__ __forceinline__ void async16(const void* g, void* l)
{
    __builtin_amdgcn_global_load_lds(
        (const __attribute__((address_space(1))) void*)g,
        (__attribute__((address_space(3))) void*)l,
        16, 0, 0);
}

__device__ __forceinline__ float bf2f(__hip_bfloat16 h) { return __bfloat162float(h); }

__device__ __forceinline__ void cvt8v(float4 a, float4 b, __hip_bfloat16* d)
{
    union { __hip_bfloat16 h[8]; short8 u; } t;
    t.h[0] = __float2bfloat16(a.x); t.h[1] = __float2bfloat16(a.y);
    t.h[2] = __float2bfloat16(a.z); t.h[3] = __float2bfloat16(a.w);
    t.h[4] = __float2bfloat16(b.x); t.h[5] = __float2bfloat16(b.y);
    t.h[6] = __float2bfloat16(b.z); t.h[7] = __float2bfloat16(b.w);
    *(short8*)d = t.u;
}

// ---------------------------------------------------------------------------
// Fused weight conversion + embedding+LN0 (extra blocks).
// blocks: [0,2048) ipw | [2048,3072) opw | [3072,3200) dtw |
//         [3200,3456) xpw(padded 256 rows) | [3456,5504) embed+LN rows
// ---------------------------------------------------------------------------
__global__ __launch_bounds__(256)
void wconv_embed_k(const float* __restrict__ ipw, const float* __restrict__ opw,
                   const float* __restrict__ dtw, const float* __restrict__ xpw,
                   __hip_bfloat16* __restrict__ ipb, __hip_bfloat16* __restrict__ opb,
                   __hip_bfloat16* __restrict__ dtb, __hip_bfloat16* __restrict__ xpb,
                   const int* __restrict__ tokens, const float* __restrict__ te,
                   const float* __restrict__ pe, const float* __restrict__ lw,
                   const float* __restrict__ lb, float* __restrict__ h,
                   __hip_bfloat16* __restrict__ xout)
{
    __shared__ float red[8];
    int blk = blockIdx.x;
    int tid = threadIdx.x;
    if (blk < 3456) {
        const float* src; __hip_bfloat16* dst; size_t base; bool xpad = false;
        if (blk < 2048)      { src = ipw; dst = ipb; base = (size_t)blk * 8192; }
        else if (blk < 3072) { src = opw; dst = opb; base = (size_t)(blk - 2048) * 8192; }
        else if (blk < 3200) { src = dtw; dst = dtb; base = (size_t)(blk - 3072) * 8192; }
        else                 { src = xpw; dst = xpb; base = (size_t)(blk - 3200) * 8192; xpad = true; }
        float4 v[8];
        size_t off[4];
        #pragma unroll
        for (int g = 0; g < 4; ++g) {
            size_t i = base + (size_t)g * 2048 + tid * 8;
            off[g] = i;
            if (!xpad) {
                v[2*g]   = *(const float4*)(src + i);
                v[2*g+1] = *(const float4*)(src + i + 4);
            } else {
                int col   = (int)(i & 2047);
                int row   = (int)((i >> 11) & 255);
                int layer = (int)(i >> 19);
                if (row < XPD_) {
                    const float* s = src + ((size_t)layer * XPD_ + row) * 2048 + col;
                    v[2*g]   = *(const float4*)s;
                    v[2*g+1] = *(const float4*)(s + 4);
                } else {
                    v[2*g] = v[2*g+1] = make_float4(0.f, 0.f, 0.f, 0.f);
                }
            }
        }
        #pragma unroll
        for (int g = 0; g < 4; ++g)
            cvt8v(v[2*g], v[2*g+1], dst + off[g]);
        return;
    }
    // ---- embedding + layer-0 LN
    int bl = blk - 3456;
    int l  = bl & (L_ - 1);
    int tok = tokens[bl];
    float4 a = *(const float4*)(te + (size_t)tok * DM_ + tid * 4);
    float4 p = *(const float4*)(pe + (size_t)l * DM_ + tid * 4);
    float4 x = make_float4(a.x + p.x, a.y + p.y, a.z + p.z, a.w + p.w);
    size_t base = (size_t)bl * DM_ + tid * 4;
    *(float4*)(h + base) = x;

    float s  = x.x + x.y + x.z + x.w;
    float s2 = x.x * x.x + x.y * x.y + x.z * x.z + x.w * x.w;
    #pragma unroll
    for (int o = 32; o > 0; o >>= 1) {
        s  += __shfl_down(s, o);
        s2 += __shfl_down(s2, o);
    }
    if ((tid & 63) == 0) { red[tid >> 6] = s; red[4 + (tid >> 6)] = s2; }
    __syncthreads();
    float st  = red[0] + red[1] + red[2] + red[3];
    float s2t = red[4] + red[5] + red[6] + red[7];
    float m   = st * (1.f / DM_);
    float var = s2t * (1.f / DM_) - m * m;
    float rs  = rsqrtf(var + 1e-5f);
    float4 wv = *(const float4*)(lw + tid * 4);
    float4 bv = *(const float4*)(lb + tid * 4);
    union { __hip_bfloat16 h[4]; ushort4 u; } t;
    t.h[0] = __float2bfloat16((x.x - m) * rs * wv.x + bv.x);
    t.h[1] = __float2bfloat16((x.y - m) * rs * wv.y + bv.y);
    t.h[2] = __float2bfloat16((x.z - m) * rs * wv.z + bv.z);
    t.h[3] = __float2bfloat16((x.w - m) * rs * wv.w + bv.w);
    *(ushort4*)(xout + base) = t.u;
}

// ---------------------------------------------------------------------------
// bf16 MFMA GEMM, 128xTN tile, BK=64 staged as TWO BK=32 LDS images
// (keeps 64B row stride to avoid 16-way ds_read conflicts; halves barriers).
// MODE 0: full-K -> bf16 C
// MODE 2: split-K partial -> fp32 Cp[z][M][ldc]
// MODE 3: split-K partial fp32 with epilogue col<Nb guard (B rows pre-padded)
// MODE 5: full-K, bias+softplus -> bf16 C (dt matmul)
// Kp (modes 0/5: full K; modes 2/3: per-part K) must be a multiple of 64.
// ---------------------------------------------------------------------------
template<int MODE, int TN>
__global__ __launch_bounds__(256)
void gemm_bf16(const __hip_bfloat16* __restrict__ A, int lda,
               const __hip_bfloat16* __restrict__ Bw, int ldb,
               void* __restrict__ Cv, int ldc, int Kp, int Nb,
               const float* __restrict__ bias)
{
    constexpr int JW = (TN == 128) ? 4 : 2;
    __shared__ __hip_bfloat16 As[2][128 * 32];
    __shared__ __hip_bfloat16 Bs[2][TN * 32];
    const int tid  = threadIdx.x;
    const int lane = tid & 63;
    const int wid  = tid >> 6;
    const int wm   = wid >> 1, wn = wid & 1;
    const int mbase = blockIdx.y * 128;
    const int nbase = blockIdx.x * TN;
    const int koff  = (MODE == 2 || MODE == 3) ? blockIdx.z * Kp : 0;

    floatx4 acc[4][JW] = {};

    const int f0 = tid * 16;
    const int r0 = f0 >> 6, c0 = f0 & 63;
    const int f1 = f0 + 4096;
    const int r1 = f1 >> 6, c1 = f1 & 63;

    const int fr = lane & 15;
    const int kq = (lane >> 4) * 8;

    for (int k0 = koff; k0 < koff + Kp; k0 += 64) {
        const char* Ag0 = (const char*)(A + (size_t)mbase * lda + k0);
        const char* Bg0 = (const char*)(Bw + (size_t)nbase * ldb + k0);
        #pragma unroll
        for (int hh = 0; hh < 2; ++hh) {
            const char* Ag = Ag0 + hh * 64;   // +32 bf16 cols
            const char* Bg = Bg0 + hh * 64;
            async16(Ag + (size_t)r0 * lda * 2 + c0, (char*)As[hh] + f0);
            async16(Ag + (size_t)r1 * lda * 2 + c1, (char*)As[hh] + f1);
            async16(Bg + (size_t)r0 * ldb * 2 + c0, (char*)Bs[hh] + f0);
            if constexpr (TN == 128)
                async16(Bg + (size_t)r1 * ldb * 2 + c1, (char*)Bs[hh] + f1);
        }
        __syncthreads();

        #pragma unroll
        for (int hh = 0; hh < 2; ++hh) {
            short8 af[4], bf[JW];
            #pragma unroll
            for (int i = 0; i < 4; ++i) {
                int m = wm * 64 + i * 16 + fr;
                af[i] = *(const short8*)(As[hh] + m * 32 + kq);
            }
            #pragma unroll
            for (int j = 0; j < JW; ++j) {
                int n = wn * (TN / 2) + j * 16 + fr;
                bf[j] = *(const short8*)(Bs[hh] + n * 32 + kq);
            }
            #pragma unroll
            for (int i = 0; i < 4; ++i)
                #pragma unroll
                for (int j = 0; j < JW; ++j)
                    acc[i][j] = __builtin_amdgcn_mfma_f32_16x16x32_bf16(
                        af[i], bf[j], acc[i][j], 0, 0, 0);
        }
        __syncthreads();
    }

    const int cq = lane >> 4;
    float* Cf = (float*)Cv;
    __hip_bfloat16* Ch = (__hip_bfloat16*)Cv;
    size_t zoff = (MODE == 2 || MODE == 3)
                ? (size_t)blockIdx.z * (gridDim.y * 128) * ldc : 0;
    #pragma unroll
    for (int i = 0; i < 4; ++i) {
        #pragma unroll
        for (int j = 0; j < JW; ++j) {
            int col = nbase + wn * (TN / 2) + j * 16 + fr;
            if (MODE == 3 && col >= Nb) continue;
            float bv = (MODE == 5) ? bias[col] : 0.f;
            #pragma unroll
            for (int r = 0; r < 4; ++r) {
                int row = mbase + wm * 64 + i * 16 + cq * 4 + r;
                float v = acc[i][j][r];
                size_t off = zoff + (size_t)row * ldc + col;
                if (MODE == 2 || MODE == 3) {
                    Cf[off] = v;
                } else if (MODE == 5) {
                    v += bv;
                    v = (v > 20.f) ? v : log1pf(__expf(v));
                    Ch[off] = __float2bfloat16(v);
                } else {
                    Ch[off] = __float2bfloat16(v);
                }
            }
        }
    }
}

// ---------------------------------------------------------------------------
// Split-K reduce for xp: emit fp32 xp AND bf16 xp_b
// ---------------------------------------------------------------------------
template<int PARTS>
__global__ __launch_bounds__(256)
void reduce_xp_k(const float* __restrict__ p, float* __restrict__ dst,
                 __hip_bfloat16* __restrict__ dst_b, size_t stride)
{
    size_t i = ((size_t)blockIdx.x * 256 + threadIdx.x) * 4;
    float4 s = *(const float4*)(p + i);
    #pragma unroll
    for (int z = 1; z < PARTS; ++z) {
        float4 v = *(const float4*)(p + z * stride + i);
        s.x += v.x; s.y += v.y; s.z += v.z; s.w += v.w;
    }
    *(float4*)(dst + i) = s;
    union { __hip_bfloat16 h[4]; ushort4 u; } t;
    t.h[0] = __float2bfloat16(s.x);
    t.h[1] = __float2bfloat16(s.y);
    t.h[2] = __float2bfloat16(s.z);
    t.h[3] = __float2bfloat16(s.w);
    *(ushort4*)(dst_b + i) = t.u;
}

// ---------------------------------------------------------------------------
// Fused: h[row] += sum_z part[z][row]; then LayerNorm(h[row]) -> bf16 out.
// ---------------------------------------------------------------------------
template<int PARTS>
__global__ __launch_bounds__(256)
void reduce_ln_k(const float* __restrict__ p, float* __restrict__ h,
                 const float* __restrict__ w, const float* __restrict__ b,
                 __hip_bfloat16* __restrict__ out, size_t stride)
{
    __shared__ float red[8];
    int tid = threadIdx.x;
    size_t base = (size_t)blockIdx.x * DM_ + tid * 4;
    float4 x = *(const float4*)(h + base);
    #pragma unroll
    for (int z = 0; z < PARTS; ++z) {
        float4 v = *(const float4*)(p + z * stride + base);
        x.x += v.x; x.y += v.y; x.z += v.z; x.w += v.w;
    }
    *(float4*)(h + base) = x;

    float s  = x.x + x.y + x.z + x.w;
    float s2 = x.x * x.x + x.y * x.y + x.z * x.z + x.w * x.w;
    #pragma unroll
    for (int o = 32; o > 0; o >>= 1) {
        s  += __shfl_down(s, o);
        s2 += __shfl_down(s2, o);
    }
    if ((tid & 63) == 0) { red[tid >> 6] = s; red[4 + (tid >> 6)] = s2; }
    __syncthreads();
    float st  = red[0] + red[1] + red[2] + red[3];
    float s2t = red[4] + red[5] + red[6] + red[7];
    float m   = st * (1.f / DM_);
    float var = s2t * (1.f / DM_) - m * m;
    float rs  = rsqrtf(var + 1e-5f);
    float4 wv = *(const float4*)(w + tid * 4);
    float4 bv = *(const float4*)(b + tid * 4);
    union { __hip_bfloat16 h[4]; ushort4 u; } t;
    t.h[0] = __float2bfloat16((x.x - m) * rs * wv.x + bv.x);
    t.h[1] = __float2bfloat16((x.y - m) * rs * wv.y + bv.y);
    t.h[2] = __float2bfloat16((x.z - m) * rs * wv.z + bv.z);
    t.h[3] = __float2bfloat16((x.w - m) * rs * wv.w + bv.w);
    *(ushort4*)(out + base) = t.u;
}

// ---------------------------------------------------------------------------
// Causal depthwise conv (K=4) + SiLU; bf16 in/out, 8 channels/thread (16B)
// ---------------------------------------------------------------------------
__global__ __launch_bounds__(256)
void conv_silu(const __hip_bfloat16* __restrict__ xz, const float* __restrict__ cw,
               const float* __restrict__ cb, __hip_bfloat16* __restrict__ xb_b)
{
    int idx = blockIdx.x * 256 + threadIdx.x;    // over B*L*(DI/8)
    int d  = (idx & 255) << 3;
    int bl = idx >> 8;
    int l  = bl & (L_ - 1);
    float4 w[8];
    #pragma unroll
    for (int j = 0; j < 8; ++j) w[j] = *(const float4*)(cw + (d + j) * 4);
    float acc[8];
    {
        float4 b0 = *(const float4*)(cb + d);
        float4 b1 = *(const float4*)(cb + d + 4);
        acc[0] = b0.x; acc[1] = b0.y; acc[2] = b0.z; acc[3] = b0.w;
        acc[4] = b1.x; acc[5] = b1.y; acc[6] = b1.z; acc[7] = b1.w;
    }
    #pragma unroll
    for (int k = 0; k < 4; ++k) {
        int lk = l + k - 3;
        if (lk >= 0) {
            union { short8 u; __hip_bfloat16 h[8]; } xu;
            xu.u = *(const short8*)(xz + (size_t)(bl - l + lk) * (2 * DI_) + d);
            #pragma unroll
            for (int j = 0; j < 8; ++j)
                acc[j] += ((const float*)&w[j])[k] * bf2f(xu.h[j]);
        }
    }
    union { __hip_bfloat16 h[8]; short8 u; } t;
    #pragma unroll
    for (int j = 0; j < 8; ++j) {
        float v = acc[j] / (1.f + __expf(-acc[j]));
        t.h[j] = __float2bfloat16(v);
    }
    *(short8*)(xb_b + (size_t)bl * DI_ + d) = t.u;
}

// ---------------------------------------------------------------------------
// SSM pass1: per-chunk local scan from 0 -> decay product Pc, local state Sc
// ---------------------------------------------------------------------------
__global__ __launch_bounds__(256)
void ssm_pass1(const __hip_bfloat16* __restrict__ xb_b,
               const __hip_bfloat16* __restrict__ dlt_b,
               const float* __restrict__ xp, const float* __restrict__ Alog,
               float* __restrict__ Pc, float* __restrict__ Sc)
{
    int blk = blockIdx.x;
    int dgrp = blk & 7, c = (blk >> 3) & 7, b = blk >> 6;
    int d = (dgrp << 8) + threadIdx.x;
    __shared__ float Bsh[CHUNK_][N_];
    for (int i = threadIdx.x; i < CHUNK_ * N_; i += 256) {
        int t = i >> 4, n = i & 15;
        Bsh[t][n] = xp[(size_t)(b * L_ + c * CHUNK_ + t) * XPD_ + DTR_ + n];
    }
    __syncthreads();
    float a[N_], hn[N_], Pn[N_];
    #pragma unroll
    for (int n = 0; n < N_; ++n) {
        a[n] = -__expf(Alog[d * N_ + n]);
        hn[n] = 0.f; Pn[n] = 1.f;
    }
    for (int t = 0; t < CHUNK_; ++t) {
        size_t off = (size_t)(b * L_ + c * CHUNK_ + t) * DI_ + d;
        float dt = bf2f(dlt_b[off]);
        float xv = bf2f(xb_b[off]);
        float dx = dt * xv;
        #pragma unroll
        for (int n = 0; n < N_; ++n) {
            float dA = __expf(dt * a[n]);
            hn[n] = dA * hn[n] + dx * Bsh[t][n];
            Pn[n] *= dA;
        }
    }
    #pragma unroll
    for (int n = 0; n < N_; ++n) {
        size_t o = ((size_t)((b * NC_ + c) * N_ + n)) * DI_ + d;
        Pc[o] = Pn[n]; Sc[o] = hn[n];
    }
}

// ---------------------------------------------------------------------------
// SSM pass2: prefix over earlier chunks (Pc/Sc L2-hot); re-run chunk;
// y = (C.h + x*D) * silu(z) -> bf16
// ---------------------------------------------------------------------------
__global__ __launch_bounds__(256)
void ssm_pass2(const __hip_bfloat16* __restrict__ xb_b,
               const __hip_bfloat16* __restrict__ dlt_b,
               const float* __restrict__ xp, const float* __restrict__ Alog,
               const float* __restrict__ Dp, const __hip_bfloat16* __restrict__ xz,
               const float* __restrict__ Pc, const float* __restrict__ Sc,
               __hip_bfloat16* __restrict__ yout)
{
    int blk = blockIdx.x;
    int dgrp = blk & 7, c = (blk >> 3) & 7, b = blk >> 6;
    int d = (dgrp << 8) + threadIdx.x;
    __shared__ float Bsh[CHUNK_][N_], Csh[CHUNK_][N_];
    for (int i = threadIdx.x; i < CHUNK_ * 2 * N_; i += 256) {
        int t = i >> 5, j = i & 31;
        float v = xp[(size_t)(b * L_ + c * CHUNK_ + t) * XPD_ + DTR_ + j];
        if (j < 16) Bsh[t][j] = v; else Csh[t][j - 16] = v;
    }
    __syncthreads();
    float a[N_], hn[N_];
    #pragma unroll
    for (int n = 0; n < N_; ++n) {
        a[n] = -__expf(Alog[d * N_ + n]);
        hn[n] = 0.f;
    }
    for (int cp = 0; cp < c; ++cp) {
        #pragma unroll
        for (int n = 0; n < N_; ++n) {
            size_t o = ((size_t)((b * NC_ + cp) * N_ + n)) * DI_ + d;
            hn[n] = Pc[o] * hn[n] + Sc[o];
        }
    }
    float dpv = Dp[d];
    for (int t = 0; t < CHUNK_; ++t) {
        int l = c * CHUNK_ + t;
        size_t off = (size_t)(b * L_ + l) * DI_ + d;
        float dt = bf2f(dlt_b[off]);
        float xv = bf2f(xb_b[off]);
        float dx = dt * xv;
        float yv = 0.f;
        #pragma unroll
        for (int n = 0; n < N_; ++n) {
            float dA = __expf(dt * a[n]);
            hn[n] = dA * hn[n] + dx * Bsh[t][n];
            yv += hn[n] * Csh[t][n];
        }
        yv += xv * dpv;
        float z = bf2f(xz[(size_t)(b * L_ + l) * (2 * DI_) + DI_ + d]);
        yout[off] = __float2bfloat16(yv * z / (1.f + __expf(-z)));
    }
}

// ---------------------------------------------------------------------------
// Fused last-layer part-sum + final LayerNorm + head.
// ---------------------------------------------------------------------------
__global__ __launch_bounds__(256)
void head_ln_k(const float* __restrict__ h, const float* __restrict__ parts,
               size_t pstride,
               const float* __restrict__ fw, const float* __restrict__ fb,
               const float* __restrict__ hw, float* __restrict__ out)
{
    __shared__ float red[4][5];
    int b = blockIdx.x / P_;
    int p = blockIdx.x % P_;
    int tid = threadIdx.x;
    size_t rowoff = ((size_t)(b * L_ + L_ - 1)) * DM_ + tid * 4;
    float4 x  = *(const float4*)(h + rowoff);
    float4 p0 = *(const float4*)(parts + rowoff);
    float4 p1 = *(const float4*)(parts + pstride + rowoff);
    x.x += p0.x + p1.x; x.y += p0.y + p1.y;
    x.z += p0.z + p1.z; x.w += p0.w + p1.w;
    float4 w4 = *(const float4*)(fw + tid * 4);
    float4 b4 = *(const float4*)(fb + tid * 4);
    float4 g4 = *(const float4*)(hw + (size_t)p * DM_ + tid * 4);
    float s  = x.x + x.y + x.z + x.w;
    float s2 = x.x * x.x + x.y * x.y + x.z * x.z + x.w * x.w;
    float t1 = x.x * w4.x * g4.x + x.y * w4.y * g4.y + x.z * w4.z * g4.z + x.w * w4.w * g4.w;
    float t2 = w4.x * g4.x + w4.y * g4.y + w4.z * g4.z + w4.w * g4.w;
    float t3 = b4.x * g4.x + b4.y * g4.y + b4.z * g4.z + b4.w * g4.w;
    #pragma unroll
    for (int o = 32; o > 0; o >>= 1) {
        s  += __shfl_down(s, o);
        s2 += __shfl_down(s2, o);
        t1 += __shfl_down(t1, o);
        t2 += __shfl_down(t2, o);
        t3 += __shfl_down(t3, o);
    }
    if ((tid & 63) == 0) {
        int w = tid >> 6;
        red[w][0] = s; red[w][1] = s2; red[w][2] = t1; red[w][3] = t2; red[w][4] = t3;
    }
    __syncthreads();
    if (tid == 0) {
        float st  = red[0][0] + red[1][0] + red[2][0] + red[3][0];
        float s2t = red[0][1] + red[1][1] + red[2][1] + red[3][1];
        float t1t = red[0][2] + red[1][2] + red[2][2] + red[3][2];
        float t2t = red[0][3] + red[1][3] + red[2][3] + red[3][3];
        float t3t = red[0][4] + red[1][4] + red[2][4] + red[3][4];
        float m   = st * (1.f / DM_);
        float var = s2t * (1.f / DM_) - m * m;
        float rs  = rsqrtf(var + 1e-5f);
        out[blockIdx.x] = rs * (t1t - m * t2t) + t3t;
    }
}

// ---------------------------------------------------------------------------
extern "C" void kernel_launch(void* const* d_in, const int* in_sizes, int n_in,
                              void* d_out, int out_size, void* d_ws, size_t ws_size,
                              hipStream_t stream)
{
    const int*   tokens     = (const int*)  d_in[0];
    const float* tok_emb    = (const float*)d_in[1];
    const float* pos_emb    = (const float*)d_in[2];
    const float* ln_w       = (const float*)d_in[3];
    const float* ln_b       = (const float*)d_in[4];
    const float* in_proj_w  = (const float*)d_in[5];
    const float* conv_w     = (const float*)d_in[6];
    const float* conv_b     = (const float*)d_in[7];
    const float* xproj_w    = (const float*)d_in[8];
    const float* dt_w       = (const float*)d_in[9];
    const float* dt_b       = (const float*)d_in[10];
    const float* A_log      = (const float*)d_in[11];
    const float* D_param    = (const float*)d_in[12];
    const float* out_proj_w = (const float*)d_in[13];
    const float* fnorm_w    = (const float*)d_in[14];
    const float* fnorm_b    = (const float*)d_in[15];
    const float* head_w     = (const float*)d_in[16];
    float* out = (float*)d_out;
    float* ws  = (float*)d_ws;

    // fp32 workspace (floats)
    float* h      = ws;                   // B*L*DM    = 2,097,152
    float* xp     = h    + 2097152;       // B*L*XPD   =   327,680
    float* Pc     = xp   + 327680;        // B*NC*N*DI = 2,097,152
    float* Sc     = Pc   + 2097152;       // 2,097,152
    float* part_h = Sc   + 2097152;       // 2 x B*L*DM = 4,194,304
    // bf16 workspace
    __hip_bfloat16* bfb = (__hip_bfloat16*)(part_h + 4194304);
    __hip_bfloat16* xz_b  = bfb;                 // B*L*2DI = 8,388,608 el
    __hip_bfloat16* xln_b = xz_b  + 8388608;     // B*L*DM  = 2,097,152 el
    __hip_bfloat16* y_b   = xln_b + 2097152;     // B*L*DI  = 4,194,304 el
    __hip_bfloat16* xb_b  = y_b   + 4194304;     // B*L*DI  = 4,194,304 el
    __hip_bfloat16* dlt_b = xb_b  + 4194304;     // B*L*DI  = 4,194,304 el
    __hip_bfloat16* xp_b  = dlt_b + 4194304;     // B*L*XPD =   327,680 el
    __hip_bfloat16* dtw_b = xp_b  + 327680;      // NL*DI*DTR = 1,048,576 el
    __hip_bfloat16* ipw_b = dtw_b + 1048576;     // NL*2DI*DM = 16,777,216 el
    __hip_bfloat16* opw_b = ipw_b + 16777216;    // NL*DM*DI  =  8,388,608 el
    __hip_bfloat16* xpw_b = opw_b + 8388608;     // NL*256*2048 = 2,097,152 el
    // split-K partials for xproj alias Pc+Sc (dead until ssm_pass1)
    float* part_xp = Pc;   // 8 x 2048 x 160 = 2,621,440 fl <= 4,194,304 fl

    // ---- weights -> bf16 + embedding + layer-0 LN
    wconv_embed_k<<<3456 + B_ * L_, 256, 0, stream>>>(
        in_proj_w, out_proj_w, dt_w, xproj_w, ipw_b, opw_b, dtw_b, xpw_b,
        tokens, tok_emb, pos_emb, ln_w, ln_b, h, xln_b);

    for (int li = 0; li < NL_; ++li) {
        // xz = x @ in_proj_w^T  (2048 x 4096, K=1024) -> bf16 [TN=64, BK=64]
        gemm_bf16<0, 64><<<dim3(2 * DI_ / 64, B_ * L_ / 128), 256, 0, stream>>>(
            xln_b, DM_, ipw_b + (size_t)li * 2 * DI_ * DM_, DM_,
            xz_b, 2 * DI_, DM_, 0, nullptr);

        // x_branch = silu(conv(xz[...,:DI]))  -> bf16 (8 ch/thread)
        conv_silu<<<B_ * L_ * DI_ / 8 / 256, 256, 0, stream>>>(
            xz_b, conv_w + li * DI_ * K_, conv_b + li * DI_, xb_b);

        // xp = x_branch @ xproj_w^T  (2048 x 160, K=2048) [TN=128 splitK-8]
        gemm_bf16<3, 128><<<dim3(2, B_ * L_ / 128, 8), 256, 0, stream>>>(
            xb_b, DI_, xpw_b + (size_t)li * 256 * 2048, DI_,
            part_xp, XPD_, DI_ / 8, XPD_, nullptr);
        reduce_xp_k<8><<<B_ * L_ * XPD_ / 1024, 256, 0, stream>>>(
            part_xp, xp, xp_b, (size_t)B_ * L_ * XPD_);

        // delta = softplus(dt_r @ dt_w^T + dt_b) (2048x2048, K=128) [TN=64]
        gemm_bf16<5, 64><<<dim3(DI_ / 64, B_ * L_ / 128), 256, 0, stream>>>(
            xp_b, XPD_, dtw_b + (size_t)li * DI_ * DTR_, DTR_,
            dlt_b, DI_, DTR_, 0, dt_b + li * DI_);

        // chunked selective scan
        ssm_pass1<<<B_ * NC_ * (DI_ / 256), 256, 0, stream>>>(
            xb_b, dlt_b, xp, A_log + li * DI_ * N_, Pc, Sc);
        ssm_pass2<<<B_ * NC_ * (DI_ / 256), 256, 0, stream>>>(
            xb_b, dlt_b, xp, A_log + li * DI_ * N_, D_param + li * DI_,
            xz_b, Pc, Sc, y_b);

        // h += y @ out_proj_w^T  (2048 x 1024, K=2048) [TN=64 splitK-2]
        gemm_bf16<2, 64><<<dim3(DM_ / 64, B_ * L_ / 128, 2), 256, 0, stream>>>(
            y_b, DI_, opw_b + (size_t)li * DM_ * DI_, DI_,
            part_h, DM_, DI_ / 2, 0, nullptr);

        if (li < NL_ - 1) {
            reduce_ln_k<2><<<B_ * L_, 256, 0, stream>>>(
                part_h, h, ln_w + (li + 1) * DM_, ln_b + (li + 1) * DM_,
                xln_b, (size_t)B_ * L_ * DM_);
        }
    }

    // fused last-layer residual + final LN + head
    head_ln_k<<<B_ * P_, 256, 0, stream>>>(
        h, part_h, (size_t)B_ * L_ * DM_, fnorm_w, fnorm_b, head_w, out);
}